// Round 3
// baseline (422.729 us; speedup 1.0000x reference)
//
#include <hip/hip_runtime.h>

// MultiHeadLinearAttention (B=8,S=4096,IN=1024,H=16,D=64). ALL I/O fp32.
//   k = x@wk + bk ; K = elu(k)+1 ; v = x@wv + bv
//   KV[b,c] = sum_s K*v (elementwise), Ksum[b,c] = sum_s K
//   out[b,s,:] = gelu_tanh((KV_b/Ksum_b)@wo + bo) — s-independent broadcast.
// v5: v3's proven all-gload_lds staging skeleton (8 counted vmem ops/STAGE,
//   zero staging regs — no spill risk to corrupt manual vmcnt) + v4's compute
//   upgrades: 32x32x16 MFMA, 2 phases/tile of 16-MFMA clusters, simplified
//   epilogue, fused rowgemm+broadcast. v4's reg-staged A (race via
//   spill-polluted vmcnt) reverted; cvt_x prepass restored.

#define SEQ   4096
#define MROWS 32768
#define KDIM  1024
#define HD    1024
#define TILES 16

typedef __bf16 bf16x8 __attribute__((ext_vector_type(8)));
typedef float floatx4 __attribute__((ext_vector_type(4)));
typedef float floatx16 __attribute__((ext_vector_type(16)));

__device__ __forceinline__ unsigned short f2bf(float f) {
    unsigned int u = __float_as_uint(f);
    u += 0x7fffu + ((u >> 16) & 1u);   // RNE
    return (unsigned short)(u >> 16);
}
__device__ __forceinline__ void cvt8(const float* __restrict__ p, unsigned short* d) {
    const float4 a = *(const float4*)p;
    const float4 b = *(const float4*)(p + 4);
    d[0] = f2bf(a.x); d[1] = f2bf(a.y); d[2] = f2bf(a.z); d[3] = f2bf(a.w);
    d[4] = f2bf(b.x); d[5] = f2bf(b.y); d[6] = f2bf(b.z); d[7] = f2bf(b.w);
}

typedef const __attribute__((address_space(1))) unsigned int* gas_t;
typedef __attribute__((address_space(3))) unsigned int* las_t;
__device__ __forceinline__ void async16(const void* g, void* l) {
    // one global_load_lds_dwordx4: LDS dst = readfirstlane(l) + lane*16
    __builtin_amdgcn_global_load_lds((gas_t)g, (las_t)l, 16, 0, 0);
}

// ---------- Prepass A: x fp32 -> bf16 ----------
__global__ __launch_bounds__(256)
void cvt_x(const float* __restrict__ x, unsigned short* __restrict__ xb)
{
    const size_t p = ((size_t)blockIdx.x * 256 + threadIdx.x) * 8;
    union { uint4 u; unsigned short s[8]; } o;
    cvt8(x + p, o.s);
    *(uint4*)(xb + p) = o.u;
}

// ---------- Prepass B: W[k][n] fp32 -> WT[n][k] bf16 (64x64 tiles) ----------
__global__ __launch_bounds__(256)
void transpose_w(const float* __restrict__ wk, const float* __restrict__ wv,
                 unsigned short* __restrict__ wkT, unsigned short* __restrict__ wvT)
{
    __shared__ alignas(16) unsigned short Ts[64][72];
    const float* W = blockIdx.z ? wv : wk;
    unsigned short* WT = blockIdx.z ? wvT : wkT;
    const int k0 = blockIdx.x * 64, n0 = blockIdx.y * 64;
    const int t = threadIdx.x;
    const int r4 = (t >> 4) * 4, c4 = (t & 15) * 4;
#pragma unroll
    for (int i = 0; i < 4; i++) {
        const float4 f = *(const float4*)(W + (size_t)(k0 + r4 + i) * HD + n0 + c4);
        Ts[c4 + 0][r4 + i] = f2bf(f.x);
        Ts[c4 + 1][r4 + i] = f2bf(f.y);
        Ts[c4 + 2][r4 + i] = f2bf(f.z);
        Ts[c4 + 3][r4 + i] = f2bf(f.w);
    }
    __syncthreads();
    const int rr = t >> 3, cc = (t & 7) * 8;
#pragma unroll
    for (int h = 0; h < 2; h++)
        *(uint4*)(WT + (size_t)(n0 + rr + h * 32) * KDIM + k0 + cc) =
            *(const uint4*)&Ts[rr + h * 32][cc];
}

// ---------- Kernel 1 (fast): 32x32x16 dual-B GEMM, all-gload_lds staging ----
// grid 1024 x 512 thr. BM=256 rows, BN=128 cols for BOTH K and V. BK=64.
// 8 waves as 4m x 2n; wave tile 64m x 64n per matrix; acc = 2x2x2 x f32x16.
// LDS: As[2][256][64] + Bs[2][256][64] bf16 (K rows 0-127, V rows 128-255).
// Swizzle s(row)=row&7 on 16B units, applied as pre-swizzled gload source +
// swizzled ds_read (both-sides, rule #21). 8 async16 per STAGE -> vmcnt(8).
__global__ __launch_bounds__(512, 2)
void kv_gemm_fast(const unsigned short* __restrict__ xb,
                  const unsigned short* __restrict__ wkT,
                  const unsigned short* __restrict__ wvT,
                  const float* __restrict__ bk, const float* __restrict__ bv,
                  float2* __restrict__ KVZ)
{
    __shared__ alignas(16) unsigned short As[2][256 * 64];   // 64 KiB
    __shared__ alignas(16) unsigned short Bs[2][256 * 64];   // 64 KiB

    const int t = threadIdx.x;

    // T1 bijective XCD decode: 1024 = 8 XCDs x (16 mtiles x 8 ntiles).
    const int id = blockIdx.x;
    const int xcd = id & 7, o = id >> 3;
    const int mtile = xcd * 16 + (o >> 3);   // 0..127
    const int ntile = o & 7;                 // 0..7
    const int m0 = mtile * 256;
    const int n0 = ntile * 128;
    const int b  = m0 >> 12;

    const int w = t >> 6, lane = t & 63;
    const int wm = w >> 1, wn = w & 1;       // 4m x 2n
    const int l32 = lane & 31, half = lane >> 5;

    // frag rows + swizzles (s(row)=row&7, invariant under +64/+128)
    int arow[2], asw[2], brow[2], bsw[2];
#pragma unroll
    for (int i = 0; i < 2; i++) {
        arow[i] = wm * 64 + i * 32 + l32;  asw[i] = arow[i] & 7;
        brow[i] = wn * 64 + i * 32 + l32;  bsw[i] = brow[i] & 7;
    }

    // staging: thread t covers row ch*64 + (t>>3), 16B unit (t&7);
    // source unit pre-swizzled so linear gload_lds dst + swizzled read = id.
    const int srow  = t >> 3;                    // 0..63
    const int sunit = (t & 7) ^ (srow & 7);
    const unsigned short* gA[4];
    const unsigned short* gB[4];
#pragma unroll
    for (int ch = 0; ch < 4; ch++)
        gA[ch] = xb + (size_t)(m0 + ch * 64 + srow) * KDIM + sunit * 8;
    gB[0] = wkT + (size_t)(n0 +      srow) * KDIM + sunit * 8;
    gB[1] = wkT + (size_t)(n0 + 64 + srow) * KDIM + sunit * 8;
    gB[2] = wvT + (size_t)(n0 +      srow) * KDIM + sunit * 8;
    gB[3] = wvT + (size_t)(n0 + 64 + srow) * KDIM + sunit * 8;

#define STAGE(c, tk) do {                                                     \
        const int ko_ = (tk) * 64;                                            \
        async16(gA[0] + ko_, &As[c][         t * 8]);                         \
        async16(gA[1] + ko_, &As[c][ 4096 +  t * 8]);                         \
        async16(gA[2] + ko_, &As[c][ 8192 +  t * 8]);                         \
        async16(gA[3] + ko_, &As[c][12288 +  t * 8]);                         \
        async16(gB[0] + ko_, &Bs[c][         t * 8]);                         \
        async16(gB[1] + ko_, &Bs[c][ 4096 +  t * 8]);                         \
        async16(gB[2] + ko_, &Bs[c][ 8192 +  t * 8]);                         \
        async16(gB[3] + ko_, &Bs[c][12288 +  t * 8]);                         \
    } while (0)

    STAGE(0, 0);
    STAGE(1, 1);

    floatx16 accK[2][2], accV[2][2];
#pragma unroll
    for (int i = 0; i < 2; i++)
#pragma unroll
        for (int j = 0; j < 2; j++) {
            accK[i][j] = (floatx16)(0.f);
            accV[i][j] = (floatx16)(0.f);
        }

    // tile0 ready when only tile1's 8 loads remain outstanding
    asm volatile("s_waitcnt vmcnt(8)" ::: "memory");
    __builtin_amdgcn_s_barrier();

    for (int tk = 0; tk < TILES; ++tk) {
        const int c = tk & 1;
        const unsigned short* A = As[c];
        const unsigned short* B = Bs[c];

#pragma unroll
        for (int ph = 0; ph < 2; ++ph) {
            bf16x8 af[2][2], bK[2][2], bV[2][2];
#pragma unroll
            for (int k2 = 0; k2 < 2; ++k2) {
                const int u = ((ph * 2 + k2) << 1) | half;   // 0..7
#pragma unroll
                for (int mi = 0; mi < 2; ++mi)
                    af[mi][k2] = *(const bf16x8*)&A[arow[mi] * 64 + ((u ^ asw[mi]) << 3)];
#pragma unroll
                for (int ni = 0; ni < 2; ++ni) {
                    bK[ni][k2] = *(const bf16x8*)&B[ brow[ni]        * 64 + ((u ^ bsw[ni]) << 3)];
                    bV[ni][k2] = *(const bf16x8*)&B[(brow[ni] + 128) * 64 + ((u ^ bsw[ni]) << 3)];
                }
            }
            __builtin_amdgcn_s_barrier();      // cluster waves per phase
            __builtin_amdgcn_s_setprio(1);
#pragma unroll
            for (int k2 = 0; k2 < 2; ++k2)
#pragma unroll
                for (int mi = 0; mi < 2; ++mi)
#pragma unroll
                    for (int ni = 0; ni < 2; ++ni) {
                        accK[mi][ni] = __builtin_amdgcn_mfma_f32_32x32x16_bf16(
                            af[mi][k2], bK[ni][k2], accK[mi][ni], 0, 0, 0);
                        accV[mi][ni] = __builtin_amdgcn_mfma_f32_32x32x16_bf16(
                            af[mi][k2], bV[ni][k2], accV[mi][ni], 0, 0, 0);
                    }
            __builtin_amdgcn_s_setprio(0);
        }

        __builtin_amdgcn_s_barrier();            // all waves done with buf c
        if (tk + 2 < TILES) {
            STAGE(c, tk + 2);
            asm volatile("s_waitcnt vmcnt(8)" ::: "memory"); // tile tk+1 landed
        } else if (tk == TILES - 2) {
            asm volatile("s_waitcnt vmcnt(0)" ::: "memory"); // tile 15 landed
        }
        __builtin_amdgcn_s_barrier();
    }
#undef STAGE

    // Epilogue: 32x32 C/D: col = lane&31; 16 regs + both lane-halves cover
    // the 32 rows of a frag -> sum regs, shfl_xor(32), one atomic per col.
#pragma unroll
    for (int ni = 0; ni < 2; ++ni) {
        const int colw = n0 + wn * 64 + ni * 32 + l32;
        const float bkf = bk[colw];
        const float bvf = bv[colw];
        float pKV = 0.f, pK = 0.f;
#pragma unroll
        for (int mi = 0; mi < 2; ++mi) {
#pragma unroll
            for (int r = 0; r < 16; ++r) {
                const float kv = accK[mi][ni][r] + bkf;
                const float K  = (kv > 0.f) ? (kv + 1.f) : __expf(kv);
                const float vv = accV[mi][ni][r] + bvf;
                pKV += K * vv;
                pK  += K;
            }
        }
        pKV += __shfl_xor(pKV, 32, 64);
        pK  += __shfl_xor(pK, 32, 64);
        if (half == 0) {
            atomicAdd(&KVZ[b * HD + colw].x, pKV);
            atomicAdd(&KVZ[b * HD + colw].y, pK);
        }
    }
}

// ---------- Kernel 1 (fallback, verified): fp32 staging ----------
__global__ __launch_bounds__(256)
void kv_gemm(const float* __restrict__ x,
             const float* __restrict__ wk, const float* __restrict__ bk,
             const float* __restrict__ wv, const float* __restrict__ bv,
             float2* __restrict__ KVZ)
{
    __shared__ alignas(16) unsigned short As [128][40];
    __shared__ alignas(16) unsigned short BsK[128][40];
    __shared__ alignas(16) unsigned short BsV[128][40];

    const int t = threadIdx.x;
    const int n0 = blockIdx.x * 128;
    const int m0 = blockIdx.y * 128;
    const int b  = m0 >> 12;

    const int wave = t >> 6, lane = t & 63;
    const int wm = wave >> 1, wn = wave & 1;
    const int lrow = lane & 15, quad = lane >> 4;

    floatx4 accK[4][4], accV[4][4];
#pragma unroll
    for (int i = 0; i < 4; i++)
#pragma unroll
        for (int j = 0; j < 4; j++) {
            accK[i][j] = (floatx4){0.f, 0.f, 0.f, 0.f};
            accV[i][j] = (floatx4){0.f, 0.f, 0.f, 0.f};
        }

    const int arow0 = t >> 2, akc = (t & 3) * 8;
    const int bk0 = t >> 4, bnc = (t & 15) * 8;

    for (int k0 = 0; k0 < KDIM; k0 += 32) {
        __syncthreads();
        {
            union { uint4 u; unsigned short s[8]; } ua, ub;
            cvt8(x + (size_t)(m0 + arow0) * KDIM + k0 + akc, ua.s);
            cvt8(x + (size_t)(m0 + arow0 + 64) * KDIM + k0 + akc, ub.s);
            *(uint4*)&As[arow0][akc] = ua.u;
            *(uint4*)&As[arow0 + 64][akc] = ub.u;
        }
        {
            unsigned short k0s[8], k1s[8], v0s[8], v1s[8];
            cvt8(wk + (size_t)(k0 + bk0) * HD + n0 + bnc, k0s);
            cvt8(wk + (size_t)(k0 + bk0 + 16) * HD + n0 + bnc, k1s);
            cvt8(wv + (size_t)(k0 + bk0) * HD + n0 + bnc, v0s);
            cvt8(wv + (size_t)(k0 + bk0 + 16) * HD + n0 + bnc, v1s);
#pragma unroll
            for (int j = 0; j < 8; j++) {
                BsK[bnc + j][bk0]      = k0s[j];
                BsK[bnc + j][bk0 + 16] = k1s[j];
                BsV[bnc + j][bk0]      = v0s[j];
                BsV[bnc + j][bk0 + 16] = v1s[j];
            }
        }
        __syncthreads();

        bf16x8 af[4], bfK[4], bfV[4];
#pragma unroll
        for (int mi = 0; mi < 4; mi++)
            af[mi] = *(const bf16x8*)&As[wm * 64 + mi * 16 + lrow][quad * 8];
#pragma unroll
        for (int ni = 0; ni < 4; ni++) {
            bfK[ni] = *(const bf16x8*)&BsK[wn * 64 + ni * 16 + lrow][quad * 8];
            bfV[ni] = *(const bf16x8*)&BsV[wn * 64 + ni * 16 + lrow][quad * 8];
        }
#pragma unroll
        for (int mi = 0; mi < 4; mi++)
#pragma unroll
            for (int ni = 0; ni < 4; ni++) {
                accK[mi][ni] = __builtin_amdgcn_mfma_f32_16x16x32_bf16(
                    af[mi], bfK[ni], accK[mi][ni], 0, 0, 0);
                accV[mi][ni] = __builtin_amdgcn_mfma_f32_16x16x32_bf16(
                    af[mi], bfV[ni], accV[mi][ni], 0, 0, 0);
            }
    }

#pragma unroll
    for (int ni = 0; ni < 4; ni++) {
        const int colw = n0 + wn * 64 + ni * 16 + lrow;
        const float bkf = bk[colw];
        const float bvf = bv[colw];
        float pKV = 0.f, pK = 0.f;
#pragma unroll
        for (int mi = 0; mi < 4; mi++) {
#pragma unroll
            for (int r = 0; r < 4; r++) {
                const float kk = accK[mi][ni][r] + bkf;
                const float K  = (kk > 0.f) ? (kk + 1.f) : __expf(kk);
                const float vv = accV[mi][ni][r] + bvf;
                pKV += K * vv;
                pK  += K;
            }
        }
        pKV += __shfl_xor(pKV, 16, 64);
        pKV += __shfl_xor(pKV, 32, 64);
        pK  += __shfl_xor(pK, 16, 64);
        pK  += __shfl_xor(pK, 32, 64);
        if (quad == 0) {
            atomicAdd(&KVZ[b * HD + colw].x, pKV);
            atomicAdd(&KVZ[b * HD + colw].y, pK);
        }
    }
}

// ---------- Kernel 2 (fused): gelu((KV/Ksum)@wo + bo) broadcast to out -----
// grid (8, 16, 8): block (b, o-chunk of 64, s-chunk of 512).
__global__ __launch_bounds__(256)
void rowgemm_bcast(const float2* __restrict__ KVZ,
                   const float* __restrict__ wo, const float* __restrict__ bo,
                   float* __restrict__ out)
{
    __shared__ float a[1024];
    __shared__ float red[4][64];
    __shared__ float sval[64];
    const int t = threadIdx.x;
    const int b = blockIdx.x;
    const int o0 = blockIdx.y * 64;
    const int s0 = blockIdx.z * 512;

    for (int c = t; c < 1024; c += 256) {
        const float2 z = KVZ[b * HD + c];
        a[c] = z.x / z.y;
    }
    __syncthreads();

    const int cs = t >> 6, oi = t & 63;
    float p = 0.f;
    const int cbeg = cs * 256;
    for (int c = cbeg; c < cbeg + 256; ++c)
        p += a[c] * wo[(size_t)c * HD + o0 + oi];
    red[cs][oi] = p;
    __syncthreads();

    if (t < 64) {
        float v = red[0][t] + red[1][t] + red[2][t] + red[3][t] + bo[o0 + t];
        sval[t] = 0.5f * v *
            (1.f + tanhf(0.7978845608028654f * (v + 0.044715f * v * v * v)));
    }
    __syncthreads();

    const float4 sv4 = *(const float4*)&sval[(t & 15) * 4];
    for (int r = t >> 4; r < 512; r += 16)
        *(float4*)&out[((size_t)(b * SEQ + s0 + r)) * HD + o0 + (t & 15) * 4] = sv4;
}

// ---------- Fallback epilogue kernels ----------
__global__ __launch_bounds__(256)
void rowgemm(const float2* __restrict__ KVZ,
             const float* __restrict__ wo, const float* __restrict__ bo,
             float* __restrict__ rowf)
{
    __shared__ float a[1024];
    __shared__ float red[4][64];
    const int t = threadIdx.x;
    const int b = blockIdx.x;
    const int o0 = blockIdx.y * 64;

    for (int c = t; c < 1024; c += 256) {
        const float2 z = KVZ[b * HD + c];
        a[c] = z.x / z.y;
    }
    __syncthreads();

    const int cs = t >> 6, oi = t & 63;
    float p = 0.f;
    const int cbeg = cs * 256;
    for (int c = cbeg; c < cbeg + 256; ++c)
        p += a[c] * wo[(size_t)c * HD + o0 + oi];
    red[cs][oi] = p;
    __syncthreads();

    if (t < 64) {
        float v = red[0][t] + red[1][t] + red[2][t] + red[3][t] + bo[o0 + t];
        const float g = 0.5f * v *
            (1.f + tanhf(0.7978845608028654f * (v + 0.044715f * v * v * v)));
        rowf[b * HD + o0 + t] = g;
    }
}

__global__ __launch_bounds__(256)
void broadcast_rows(const float* __restrict__ rowf, float* __restrict__ out)
{
    const size_t idx = (size_t)blockIdx.x * 256 + threadIdx.x;
    const size_t p = idx * 4;
    const int row = (int)(p >> 10);
    const int b = row >> 12;
    const int col = (int)(p & 1023);
    *(float4*)(out + p) = *(const float4*)(rowf + b * HD + col);
}

extern "C" void kernel_launch(void* const* d_in, const int* in_sizes, int n_in,
                              void* d_out, int out_size, void* d_ws, size_t ws_size,
                              hipStream_t stream)
{
    const float* x  = (const float*)d_in[0];
    const float* wk = (const float*)d_in[3];
    const float* bk = (const float*)d_in[4];
    const float* wv = (const float*)d_in[5];
    const float* bv = (const float*)d_in[6];
    const float* wo = (const float*)d_in[7];
    const float* bo = (const float*)d_in[8];
    float* out = (float*)d_out;

    const size_t NEED = (size_t)72 * 1024 * 1024;
    if (ws_size >= NEED) {
        unsigned short* xb  = (unsigned short*)d_ws;                       // 64 MiB
        unsigned short* wkT = (unsigned short*)((char*)d_ws + (67u << 20));// 2 MiB
        unsigned short* wvT = (unsigned short*)((char*)d_ws + (69u << 20));// 2 MiB
        float2* KVZ = (float2*)((char*)d_ws + (71u << 20));                // 64 KiB

        hipMemsetAsync(KVZ, 0, 8 * HD * sizeof(float2), stream);
        cvt_x<<<dim3(MROWS * KDIM / 8 / 256), 256, 0, stream>>>(x, xb);
        transpose_w<<<dim3(16, 16, 2), 256, 0, stream>>>(wk, wv, wkT, wvT);
        kv_gemm_fast<<<dim3(1024), 512, 0, stream>>>(xb, wkT, wvT, bk, bv, KVZ);
        rowgemm_bcast<<<dim3(8, 16, 8), 256, 0, stream>>>(KVZ, wo, bo, out);
    } else {
        float2* KVZ = (float2*)d_ws;
        float* rowf = (float*)((char*)d_ws + 65536);
        hipMemsetAsync(KVZ, 0, 8 * HD * sizeof(float2), stream);
        kv_gemm<<<dim3(8, 256), 256, 0, stream>>>(x, wk, bk, wv, bv, KVZ);
        rowgemm<<<dim3(8, 16), 256, 0, stream>>>(KVZ, wo, bo, rowf);
        broadcast_rows<<<dim3((MROWS * HD / 4) / 256), 256, 0, stream>>>(rowf, out);
    }
}